// Round 10
// baseline (125.806 us; speedup 1.0000x reference)
//
#include <hip/hip_runtime.h>
#include <hip/hip_bf16.h>
#include <cstdint>
#include <cstddef>

// Problem dims
#define Bb 2
#define Tt 2048
#define Dd 1024
#define Hh 16
#define DHh 64

using short8 = __attribute__((ext_vector_type(8))) short;   // 8 bf16 (4 VGPRs) MFMA operand
using f32x4  = __attribute__((ext_vector_type(4))) float;   // MFMA accumulator 16x16
typedef unsigned short u16;

// f32 -> bf16 (RNE) scalar
__device__ __forceinline__ u16 f2bf(float f) {
    unsigned int u = __float_as_uint(f);
    u += 0x7fffu + ((u >> 16) & 1u);
    return (u16)(u >> 16);
}

// pack two f32 -> bf16x2 (v_cvt_pk_bf16_f32 via HIP API)
__device__ __forceinline__ unsigned int pk2bf(float a, float b) {
    union { __hip_bfloat162 h; unsigned int u; } c;
    c.h = __float22bfloat162_rn(float2{a, b});
    return c.u;
}

// async global->LDS, 16B per lane; LDS dest is wave-uniform base + lane*16
__device__ __forceinline__ void gload16(const void* g, void* l) {
    __builtin_amdgcn_global_load_lds((const __attribute__((address_space(1))) void*)g,
                                     (__attribute__((address_space(3))) void*)l, 16, 0, 0);
}

// ---------------------------------------------------------------------------
// m97-style GEMM core: C[128x128] of A[M,K] @ BT[N,K]^T, bf16 in, f32 acc.
// ---------------------------------------------------------------------------
__device__ __forceinline__ void gemm_bt_core(const u16* __restrict__ A, const u16* __restrict__ BT,
                                             int K, int m0, int n0,
                                             u16* As, u16* Bs, f32x4 acc[4][4]) {
    const int tid = threadIdx.x;
    const int w = tid >> 6, lane = tid & 63;
    const int lr = lane & 15, lg = lane >> 4;
    const int wr = w >> 1, wc = w & 1;
    const int arow = lane >> 2;
    const int acol = (lane & 3) * 8;
    for (int kk = 0; kk < K; kk += 32) {
        __syncthreads();
#pragma unroll
        for (int j = 0; j < 2; ++j) {
            int r0 = w * 32 + j * 16;
            gload16(A  + (size_t)(m0 + r0 + arow) * K + kk + acol, (char*)As + r0 * 64);
            gload16(BT + (size_t)(n0 + r0 + arow) * K + kk + acol, (char*)Bs + r0 * 64);
        }
        __syncthreads();
        short8 af[4], bfv[4];
#pragma unroll
        for (int m = 0; m < 4; ++m)
            af[m] = *(const short8*)((const char*)As + ((wr * 64 + m * 16 + lr) * 64 + lg * 16));
#pragma unroll
        for (int n = 0; n < 4; ++n)
            bfv[n] = *(const short8*)((const char*)Bs + ((wc * 64 + n * 16 + lr) * 64 + lg * 16));
#pragma unroll
        for (int m = 0; m < 4; ++m)
#pragma unroll
            for (int n = 0; n < 4; ++n)
                acc[m][n] = __builtin_amdgcn_mfma_f32_16x16x32_bf16(af[m], bfv[n], acc[m][n], 0, 0, 0);
    }
}

// ---------------------------------------------------------------------------
// Prep: x (f32) -> bf16; data_mask (int) -> f32 additive bias (0 / -15000)
// ---------------------------------------------------------------------------
__global__ __launch_bounds__(256) void convert_x_k(const float4* __restrict__ x4,
                                                   ushort4* __restrict__ xb4, int n4,
                                                   const int* __restrict__ dmask,
                                                   float* __restrict__ dmb) {
    int i = blockIdx.x * 256 + threadIdx.x;
    if (i < n4) {
        float4 v = x4[i];
        ushort4 o;
        o.x = f2bf(v.x); o.y = f2bf(v.y); o.z = f2bf(v.z); o.w = f2bf(v.w);
        xb4[i] = o;
    }
    if (i < Bb * Tt) dmb[i] = dmask[i] ? 0.f : -15000.f;
}

// Prep: W[k][n] f32 -> WT[n][k] bf16, 4 matrices (z: Wq,Wk,Wv,Wp)
__global__ void transpose_w_k(const float* __restrict__ Wq, const float* __restrict__ Wk,
                              const float* __restrict__ Wv, const float* __restrict__ Wp,
                              u16* __restrict__ wt) {
    __shared__ float tile[32][33];
    const int z = blockIdx.z;
    const float* W = (z == 0) ? Wq : (z == 1) ? Wk : (z == 2) ? Wv : Wp;
    const int n0 = blockIdx.x * 32, k0 = blockIdx.y * 32;
    const int tx = threadIdx.x, ty = threadIdx.y;   // (32, 8)
#pragma unroll
    for (int j = 0; j < 4; ++j)
        tile[ty + j * 8][tx] = W[(size_t)(k0 + ty + j * 8) * Dd + n0 + tx];
    __syncthreads();
    u16* outp = wt + (size_t)z * Dd * Dd;
#pragma unroll
    for (int j = 0; j < 4; ++j)
        outp[(size_t)(n0 + ty + j * 8) * Dd + k0 + tx] = f2bf(tile[tx][ty + j * 8]);
}

// ---------------------------------------------------------------------------
// QKV GEMM (m97 128^2, 768 blocks): Q (scaled incl log2e), K per-head,
// V stored PRE-PERMUTED+PRE-SWIZZLED as 16KB-contiguous 128-key tiles:
// VTg[bh][kt][dh][chunk'][0..7], where tile-local position
//   pos(key a) = 32*(a>>5) + ((a&15)>>2)*8 + ((a>>4)&1)*4 + (a&3)   (PV pi)
//   chunk' = (pos>>3) ^ (dh&7)                                       (bank swz)
// ---------------------------------------------------------------------------
__global__ __launch_bounds__(256) void qkv_gemm_k(const u16* __restrict__ xb, const u16* __restrict__ wt,
        const float* __restrict__ bq, const float* __restrict__ bk, const float* __restrict__ bv,
        u16* __restrict__ Qg, u16* __restrict__ Kg, u16* __restrict__ VTg) {
    __shared__ alignas(16) u16 As[128 * 32];
    __shared__ alignas(16) u16 Bs[128 * 32];
    f32x4 acc[4][4];
    const f32x4 vzero = {0.f, 0.f, 0.f, 0.f};
#pragma unroll
    for (int m = 0; m < 4; ++m)
#pragma unroll
        for (int n = 0; n < 4; ++n) acc[m][n] = vzero;
    const int m0 = blockIdx.y * 128, n0 = blockIdx.x * 128;
    gemm_bt_core(xb, wt, 1024, m0, n0, As, Bs, acc);
    const int tid = threadIdx.x, w = tid >> 6, lane = tid & 63, lr = lane & 15, lg = lane >> 4;
    const int wr = w >> 1, wc = w & 1;
    const int sec = n0 >> 10;             // 0:Q 1:K 2:V (128-tiles never straddle)
    const float* bias = (sec == 0) ? bq : (sec == 1) ? bk : bv;
    u16* dst = (sec == 0) ? Qg : (sec == 1) ? Kg : VTg;
    // Q scale: DH^-0.5 * log2(e)  -> softmax runs in exp2 domain
    const float qscale = (sec == 0) ? 0.125f * 1.4426950408889634f : 1.0f;
#pragma unroll
    for (int n = 0; n < 4; ++n) {
        int gn = n0 + wc * 64 + n * 16 + lr;
        int j = gn & 1023;
        float bj = bias[j];
        int h = j >> 6, dh = j & 63;
#pragma unroll
        for (int m = 0; m < 4; ++m) {
            int gmb = m0 + wr * 64 + m * 16 + 4 * lg;
#pragma unroll
            for (int i = 0; i < 4; ++i) {
                int gm = gmb + i;
                int b = gm >> 11, t = gm & 2047;
                float v = (acc[m][n][i] + bj) * qscale;
                size_t off;
                if (sec < 2) off = (((size_t)(b * Hh + h)) * Tt + t) * DHh + dh;       // [bh][t][dh]
                else {
                    int kt2 = t >> 7, a = t & 127;
                    int ks2 = a >> 5, r = a & 31;
                    int pos = ks2 * 32 + ((r & 15) >> 2) * 8 + ((r >> 4) & 1) * 4 + (r & 3);
                    int chunkp = (pos >> 3) ^ (dh & 7);
                    off = (((size_t)(b * Hh + h) * 16 + kt2) * 64 + dh) * 128 + chunkp * 8 + (pos & 7);
                }
                dst[off] = f2bf(v);
            }
        }
    }
}

// ---------------------------------------------------------------------------
// Flash attention, QBLK=128: 4 waves, each wave owns TWO 16-row q-sub-tiles
// (q0 = qb*128 + w*16, q1 = q0 + 64). Per 128-key tile the staged K/V bytes
// and every K/V ds_read are shared by both sub-tiles -> per-work barrier,
// stage, ds_read and addressing costs halve vs QBLK=64 (R8).
// No-max softmax (exp2 domain); mask enters as QK C-operand (0/-15000);
// causal subtract only on the single diagonal tile (kt == qb).
// PV B-operand lane-local via pi-permuted VTg; l on the MFMA pipe.
// ---------------------------------------------------------------------------
__global__ __launch_bounds__(256, 2) void attn_k(const u16* __restrict__ Qg, const u16* __restrict__ Kg,
        const u16* __restrict__ VTg, const float* __restrict__ dmb, u16* __restrict__ Og) {
    __shared__ alignas(16) u16 Ks[128 * 64];     // [key][dh]   rows 128B, chunk-swz
    __shared__ alignas(16) u16 Vs[64 * 128];     // [dh][pos]   rows 256B, pre-swz in VTg
    const int bh = blockIdx.x;
    const int qb = (int)gridDim.y - 1 - (int)blockIdx.y;  // heavy blocks first
    const int b = bh >> 4, h = bh & 15;
    const int tid = threadIdx.x, w = tid >> 6, lane = tid & 63;
    const int lr = lane & 15, lg = lane >> 4;
    const int q0 = qb * 128 + w * 16;            // sub-tile a rows
    const int q1 = q0 + 64;                      // sub-tile b rows
    const int qrow0 = q0 + lr, qrow1 = q1 + lr;
    const u16* Qb0 = Qg + ((size_t)bh * Tt + qrow0) * DHh;
    const u16* Qb1 = Qg + ((size_t)bh * Tt + qrow1) * DHh;
    short8 qf0a = *(const short8*)(Qb0 + lg * 8);
    short8 qf1a = *(const short8*)(Qb0 + 32 + lg * 8);
    short8 qf0b = *(const short8*)(Qb1 + lg * 8);
    short8 qf1b = *(const short8*)(Qb1 + 32 + lg * 8);
    const f32x4 vzero = {0.f, 0.f, 0.f, 0.f};
    const short8 ones8 = {(short)0x3F80, (short)0x3F80, (short)0x3F80, (short)0x3F80,
                          (short)0x3F80, (short)0x3F80, (short)0x3F80, (short)0x3F80};
    f32x4 oa[4], ob[4];
#pragma unroll
    for (int n = 0; n < 4; ++n) { oa[n] = vzero; ob[n] = vzero; }
    f32x4 acc_la = vzero, acc_lb = vzero;
    const int ktiles = qb + 1;
    char* KsB = (char*)Ks; char* VsB = (char*)Vs;

    for (int kt = 0; kt < ktiles; ++kt) {
        const int kbase = kt * 128;
        __syncthreads();
        // stage K tile: wave w rows [w*32,+32), chunk-swizzled source
#pragma unroll
        for (int j = 0; j < 4; ++j) {
            int r0 = w * 32 + j * 8;
            int r = r0 + (lane >> 3);
            int cs = (lane & 7) ^ (r & 7);
            gload16(Kg + ((size_t)bh * Tt + kbase + r) * DHh + cs * 8, KsB + r0 * 128);
        }
        // stage V tile: LINEAR 4KB per wave from pre-permuted VTg
        {
            const u16* vsrc = VTg + (((size_t)bh * 16 + kt) * 8192) + w * 2048 + lane * 8;
#pragma unroll
            for (int j = 0; j < 4; ++j)
                gload16(vsrc + j * 512, VsB + w * 4096 + j * 1024);
        }
        __syncthreads();
        // S^T = K Q^T + mask-bias: K frags read ONCE, used by both sub-tiles
        f32x4 sa[8], sb[8];
        const float* bb = dmb + (size_t)b * Tt + kbase + 4 * lg;
#pragma unroll
        for (int nf = 0; nf < 8; ++nf) {
            int r = nf * 16 + lr;
            short8 k0v = *(const short8*)(KsB + r * 128 + (((0 + lg) ^ (r & 7)) << 4));
            short8 k1v = *(const short8*)(KsB + r * 128 + (((4 + lg) ^ (r & 7)) << 4));
            f32x4 cin = *(const f32x4*)(bb + nf * 16);
            f32x4 t0a = __builtin_amdgcn_mfma_f32_16x16x32_bf16(k0v, qf0a, cin, 0, 0, 0);
            sa[nf] = __builtin_amdgcn_mfma_f32_16x16x32_bf16(k1v, qf1a, t0a, 0, 0, 0);
            f32x4 t0b = __builtin_amdgcn_mfma_f32_16x16x32_bf16(k0v, qf0b, cin, 0, 0, 0);
            sb[nf] = __builtin_amdgcn_mfma_f32_16x16x32_bf16(k1v, qf1b, t0b, 0, 0, 0);
        }
        // causal cut on the single diagonal tile (wave-uniform)
        if (kt == qb) {
#pragma unroll
            for (int nf = 0; nf < 8; ++nf) {
                int tk = kbase + 16 * nf + 4 * lg;
#pragma unroll
                for (int i = 0; i < 4; ++i) {
                    if (tk + i > qrow0) sa[nf][i] -= 15000.f;
                    if (tk + i > qrow1) sb[nf][i] -= 15000.f;
                }
            }
        }
        // PV: pf lane-local; V frags read ONCE per (ks,n), feed both sub-tiles
#pragma unroll
        for (int ks = 0; ks < 4; ++ks) {
            union { uint4 u; short8 sv; } pfa, pfb;
            pfa.u.x = pk2bf(exp2f(sa[2 * ks][0]), exp2f(sa[2 * ks][1]));
            pfa.u.y = pk2bf(exp2f(sa[2 * ks][2]), exp2f(sa[2 * ks][3]));
            pfa.u.z = pk2bf(exp2f(sa[2 * ks + 1][0]), exp2f(sa[2 * ks + 1][1]));
            pfa.u.w = pk2bf(exp2f(sa[2 * ks + 1][2]), exp2f(sa[2 * ks + 1][3]));
            pfb.u.x = pk2bf(exp2f(sb[2 * ks][0]), exp2f(sb[2 * ks][1]));
            pfb.u.y = pk2bf(exp2f(sb[2 * ks][2]), exp2f(sb[2 * ks][3]));
            pfb.u.z = pk2bf(exp2f(sb[2 * ks + 1][0]), exp2f(sb[2 * ks + 1][1]));
            pfb.u.w = pk2bf(exp2f(sb[2 * ks + 1][2]), exp2f(sb[2 * ks + 1][3]));
            acc_la = __builtin_amdgcn_mfma_f32_16x16x32_bf16(ones8, pfa.sv, acc_la, 0, 0, 0);
            acc_lb = __builtin_amdgcn_mfma_f32_16x16x32_bf16(ones8, pfb.sv, acc_lb, 0, 0, 0);
#pragma unroll
            for (int n = 0; n < 4; ++n) {
                int rv = n * 16 + lr;
                short8 vf = *(const short8*)(VsB + rv * 256 + ((((ks * 4 + lg)) ^ (rv & 7)) << 4));
                oa[n] = __builtin_amdgcn_mfma_f32_16x16x32_bf16(vf, pfa.sv, oa[n], 0, 0, 0);
                ob[n] = __builtin_amdgcn_mfma_f32_16x16x32_bf16(vf, pfb.sv, ob[n], 0, 0, 0);
            }
        }
    }
    // epilogue: normalize and write both sub-tiles
    float la = acc_la[0], lb = acc_lb[0];
    float inva = la > 0.f ? 1.0f / la : 0.f;
    float invb = lb > 0.f ? 1.0f / lb : 0.f;
#pragma unroll
    for (int n = 0; n < 4; ++n) {
        uint2 pw;
        pw.x = pk2bf(oa[n][0] * inva, oa[n][1] * inva);
        pw.y = pk2bf(oa[n][2] * inva, oa[n][3] * inva);
        *(uint2*)(Og + ((size_t)(b * Tt + qrow0)) * Dd + h * DHh + n * 16 + 4 * lg) = pw;
        pw.x = pk2bf(ob[n][0] * invb, ob[n][1] * invb);
        pw.y = pk2bf(ob[n][2] * invb, ob[n][3] * invb);
        *(uint2*)(Og + ((size_t)(b * Tt + qrow1)) * Dd + h * DHh + n * 16 + 4 * lg) = pw;
    }
}

// ---------------------------------------------------------------------------
// Output GEMM: O[4096,1024] @ Wp -> f32 out, + bp, * data_mask (m97 core)
// ---------------------------------------------------------------------------
__global__ __launch_bounds__(256) void out_gemm_k(const u16* __restrict__ Og, const u16* __restrict__ wpt,
        const float* __restrict__ bp, const int* __restrict__ dmask, float* __restrict__ out) {
    __shared__ alignas(16) u16 As[128 * 32];
    __shared__ alignas(16) u16 Bs[128 * 32];
    f32x4 acc[4][4];
    const f32x4 vzero = {0.f, 0.f, 0.f, 0.f};
#pragma unroll
    for (int m = 0; m < 4; ++m)
#pragma unroll
        for (int n = 0; n < 4; ++n) acc[m][n] = vzero;
    const int m0 = blockIdx.y * 128, n0 = blockIdx.x * 128;
    gemm_bt_core(Og, wpt, 1024, m0, n0, As, Bs, acc);
    const int tid = threadIdx.x, w = tid >> 6, lane = tid & 63, lr = lane & 15, lg = lane >> 4;
    const int wr = w >> 1, wc = w & 1;
#pragma unroll
    for (int n = 0; n < 4; ++n) {
        int gn = n0 + wc * 64 + n * 16 + lr;
        float bj = bp[gn];
#pragma unroll
        for (int m = 0; m < 4; ++m) {
            int gmb = m0 + wr * 64 + m * 16 + 4 * lg;
#pragma unroll
            for (int i = 0; i < 4; ++i) {
                int gm = gmb + i;
                float dmv = (float)dmask[gm];
                out[(size_t)gm * Dd + gn] = (acc[m][n][i] + bj) * dmv;
            }
        }
    }
}

// ---------------------------------------------------------------------------
// Workspace layout (bytes):
//   [0,8M)    xb  bf16 [4096][1024]   (reused as Og after qkv_gemm)
//   [8M,16M)  wt  bf16 [4][1024][1024] (WqT,WkT,WvT,WpT)
//   [16M,24M) Qg  bf16 [32][2048][64]  (scaled incl log2e)
//   [24M,32M) Kg  bf16 [32][2048][64]
//   [32M,40M) VTg bf16 [32][16][64][128] (V pre-permuted tiled, 16KB/tile)
//   [40M,+16K) dmb f32 [2][2048] additive mask bias
// ---------------------------------------------------------------------------
extern "C" void kernel_launch(void* const* d_in, const int* in_sizes, int n_in,
                              void* d_out, int out_size, void* d_ws, size_t ws_size,
                              hipStream_t stream) {
    const float* x   = (const float*)d_in[0];
    const int*  dmask = (const int*)d_in[1];
    const float* Wq = (const float*)d_in[2];
    const float* bq = (const float*)d_in[3];
    const float* Wk = (const float*)d_in[4];
    const float* bk = (const float*)d_in[5];
    const float* Wv = (const float*)d_in[6];
    const float* bv = (const float*)d_in[7];
    const float* Wp = (const float*)d_in[8];
    const float* bp = (const float*)d_in[9];
    float* out = (float*)d_out;
    char* ws = (char*)d_ws;
    u16* xb  = (u16*)(ws);
    u16* wt  = (u16*)(ws + ((size_t)8 << 20));
    u16* Qg  = (u16*)(ws + ((size_t)16 << 20));
    u16* Kg  = (u16*)(ws + ((size_t)24 << 20));
    u16* VTg = (u16*)(ws + ((size_t)32 << 20));
    float* dmb = (float*)(ws + ((size_t)40 << 20));
    u16* Og  = xb;   // reuse: xb consumed by qkv_gemm before attn writes Og

    convert_x_k<<<dim3(4096), dim3(256), 0, stream>>>((const float4*)x, (ushort4*)xb,
                                                      (Bb * Tt * Dd) / 4, dmask, dmb);
    transpose_w_k<<<dim3(32, 32, 4), dim3(32, 8), 0, stream>>>(Wq, Wk, Wv, Wp, wt);
    qkv_gemm_k<<<dim3(24, 32), dim3(256), 0, stream>>>(xb, wt, bq, bk, bv, Qg, Kg, VTg);
    attn_k<<<dim3(32, 16), dim3(256), 0, stream>>>(Qg, Kg, VTg, dmb, Og);
    out_gemm_k<<<dim3(8, 32), dim3(256), 0, stream>>>(Og, wt + (size_t)3 * Dd * Dd, bp, dmask, out);
}

// Round 11
// 115.232 us; speedup vs baseline: 1.0918x; 1.0918x over previous
//
#include <hip/hip_runtime.h>
#include <hip/hip_bf16.h>
#include <cstdint>
#include <cstddef>

// Problem dims
#define Bb 2
#define Tt 2048
#define Dd 1024
#define Hh 16
#define DHh 64

using short8 = __attribute__((ext_vector_type(8))) short;   // 8 bf16 (4 VGPRs) MFMA operand
using f32x4  = __attribute__((ext_vector_type(4))) float;   // MFMA accumulator 16x16
typedef unsigned short u16;

// f32 -> bf16 (RNE) scalar
__device__ __forceinline__ u16 f2bf(float f) {
    unsigned int u = __float_as_uint(f);
    u += 0x7fffu + ((u >> 16) & 1u);
    return (u16)(u >> 16);
}

// pack two f32 -> bf16x2 (v_cvt_pk_bf16_f32 via HIP API)
__device__ __forceinline__ unsigned int pk2bf(float a, float b) {
    union { __hip_bfloat162 h; unsigned int u; } c;
    c.h = __float22bfloat162_rn(float2{a, b});
    return c.u;
}

// async global->LDS, 16B per lane; LDS dest is wave-uniform base + lane*16
__device__ __forceinline__ void gload16(const void* g, void* l) {
    __builtin_amdgcn_global_load_lds((const __attribute__((address_space(1))) void*)g,
                                     (__attribute__((address_space(3))) void*)l, 16, 0, 0);
}

// ---------------------------------------------------------------------------
// m97-style GEMM core: C[128x128] of A[M,K] @ BT[N,K]^T, bf16 in, f32 acc.
// ---------------------------------------------------------------------------
__device__ __forceinline__ void gemm_bt_core(const u16* __restrict__ A, const u16* __restrict__ BT,
                                             int K, int m0, int n0,
                                             u16* As, u16* Bs, f32x4 acc[4][4]) {
    const int tid = threadIdx.x;
    const int w = tid >> 6, lane = tid & 63;
    const int lr = lane & 15, lg = lane >> 4;
    const int wr = w >> 1, wc = w & 1;
    const int arow = lane >> 2;
    const int acol = (lane & 3) * 8;
    for (int kk = 0; kk < K; kk += 32) {
        __syncthreads();
#pragma unroll
        for (int j = 0; j < 2; ++j) {
            int r0 = w * 32 + j * 16;
            gload16(A  + (size_t)(m0 + r0 + arow) * K + kk + acol, (char*)As + r0 * 64);
            gload16(BT + (size_t)(n0 + r0 + arow) * K + kk + acol, (char*)Bs + r0 * 64);
        }
        __syncthreads();
        short8 af[4], bfv[4];
#pragma unroll
        for (int m = 0; m < 4; ++m)
            af[m] = *(const short8*)((const char*)As + ((wr * 64 + m * 16 + lr) * 64 + lg * 16));
#pragma unroll
        for (int n = 0; n < 4; ++n)
            bfv[n] = *(const short8*)((const char*)Bs + ((wc * 64 + n * 16 + lr) * 64 + lg * 16));
#pragma unroll
        for (int m = 0; m < 4; ++m)
#pragma unroll
            for (int n = 0; n < 4; ++n)
                acc[m][n] = __builtin_amdgcn_mfma_f32_16x16x32_bf16(af[m], bfv[n], acc[m][n], 0, 0, 0);
    }
}

// ---------------------------------------------------------------------------
// Prep: x (f32) -> bf16; data_mask (int) -> f32 additive bias (0 / -15000)
// ---------------------------------------------------------------------------
__global__ __launch_bounds__(256) void convert_x_k(const float4* __restrict__ x4,
                                                   ushort4* __restrict__ xb4, int n4,
                                                   const int* __restrict__ dmask,
                                                   float* __restrict__ dmb) {
    int i = blockIdx.x * 256 + threadIdx.x;
    if (i < n4) {
        float4 v = x4[i];
        ushort4 o;
        o.x = f2bf(v.x); o.y = f2bf(v.y); o.z = f2bf(v.z); o.w = f2bf(v.w);
        xb4[i] = o;
    }
    if (i < Bb * Tt) dmb[i] = dmask[i] ? 0.f : -15000.f;
}

// Prep: W[k][n] f32 -> WT[n][k] bf16, 4 matrices (z: Wq,Wk,Wv,Wp)
__global__ void transpose_w_k(const float* __restrict__ Wq, const float* __restrict__ Wk,
                              const float* __restrict__ Wv, const float* __restrict__ Wp,
                              u16* __restrict__ wt) {
    __shared__ float tile[32][33];
    const int z = blockIdx.z;
    const float* W = (z == 0) ? Wq : (z == 1) ? Wk : (z == 2) ? Wv : Wp;
    const int n0 = blockIdx.x * 32, k0 = blockIdx.y * 32;
    const int tx = threadIdx.x, ty = threadIdx.y;   // (32, 8)
#pragma unroll
    for (int j = 0; j < 4; ++j)
        tile[ty + j * 8][tx] = W[(size_t)(k0 + ty + j * 8) * Dd + n0 + tx];
    __syncthreads();
    u16* outp = wt + (size_t)z * Dd * Dd;
#pragma unroll
    for (int j = 0; j < 4; ++j)
        outp[(size_t)(n0 + ty + j * 8) * Dd + k0 + tx] = f2bf(tile[tx][ty + j * 8]);
}

// ---------------------------------------------------------------------------
// QKV GEMM (m97 128^2, 768 blocks): Q (scaled incl log2e), K per-head,
// V stored PRE-PERMUTED+PRE-SWIZZLED as 16KB-contiguous 128-key tiles:
// VTg[bh][kt][dh][chunk'][0..7], where tile-local position
//   pos(key a) = 32*(a>>5) + ((a&15)>>2)*8 + ((a>>4)&1)*4 + (a&3)   (PV pi)
//   chunk' = (pos>>3) ^ (dh&7)                                       (bank swz)
// ---------------------------------------------------------------------------
__global__ __launch_bounds__(256) void qkv_gemm_k(const u16* __restrict__ xb, const u16* __restrict__ wt,
        const float* __restrict__ bq, const float* __restrict__ bk, const float* __restrict__ bv,
        u16* __restrict__ Qg, u16* __restrict__ Kg, u16* __restrict__ VTg) {
    __shared__ alignas(16) u16 As[128 * 32];
    __shared__ alignas(16) u16 Bs[128 * 32];
    f32x4 acc[4][4];
    const f32x4 vzero = {0.f, 0.f, 0.f, 0.f};
#pragma unroll
    for (int m = 0; m < 4; ++m)
#pragma unroll
        for (int n = 0; n < 4; ++n) acc[m][n] = vzero;
    const int m0 = blockIdx.y * 128, n0 = blockIdx.x * 128;
    gemm_bt_core(xb, wt, 1024, m0, n0, As, Bs, acc);
    const int tid = threadIdx.x, w = tid >> 6, lane = tid & 63, lr = lane & 15, lg = lane >> 4;
    const int wr = w >> 1, wc = w & 1;
    const int sec = n0 >> 10;             // 0:Q 1:K 2:V (128-tiles never straddle)
    const float* bias = (sec == 0) ? bq : (sec == 1) ? bk : bv;
    u16* dst = (sec == 0) ? Qg : (sec == 1) ? Kg : VTg;
    // Q scale: DH^-0.5 * log2(e)  -> softmax runs in exp2 domain
    const float qscale = (sec == 0) ? 0.125f * 1.4426950408889634f : 1.0f;
#pragma unroll
    for (int n = 0; n < 4; ++n) {
        int gn = n0 + wc * 64 + n * 16 + lr;
        int j = gn & 1023;
        float bj = bias[j];
        int h = j >> 6, dh = j & 63;
#pragma unroll
        for (int m = 0; m < 4; ++m) {
            int gmb = m0 + wr * 64 + m * 16 + 4 * lg;
#pragma unroll
            for (int i = 0; i < 4; ++i) {
                int gm = gmb + i;
                int b = gm >> 11, t = gm & 2047;
                float v = (acc[m][n][i] + bj) * qscale;
                size_t off;
                if (sec < 2) off = (((size_t)(b * Hh + h)) * Tt + t) * DHh + dh;       // [bh][t][dh]
                else {
                    int kt2 = t >> 7, a = t & 127;
                    int ks2 = a >> 5, r = a & 31;
                    int pos = ks2 * 32 + ((r & 15) >> 2) * 8 + ((r >> 4) & 1) * 4 + (r & 3);
                    int chunkp = (pos >> 3) ^ (dh & 7);
                    off = (((size_t)(b * Hh + h) * 16 + kt2) * 64 + dh) * 128 + chunkp * 8 + (pos & 7);
                }
                dst[off] = f2bf(v);
            }
        }
    }
}

// ---------------------------------------------------------------------------
// Flash attention (R8 structure + T3 2-phase prefetch double-buffer):
// 4 waves x 16 q-rows (QBLK=64), K-tile 128, grid 1024 blocks (>=4096 waves
// — the TLP floor learned in R2/R4/R9). Per tile: STAGE(next tile -> other
// buffer) issued BEFORE compute; ONE barrier per tile (vmcnt drain lands
// after compute, hiding staging latency). No-max softmax (exp2 domain);
// mask via QK C-operand bias; PV B-operand lane-local (pi-permuted VTg);
// l on the MFMA pipe. LDS 64KB = 2 buf x (K 16KB + V 16KB).
// ---------------------------------------------------------------------------
__global__ __launch_bounds__(256, 2) void attn_k(const u16* __restrict__ Qg, const u16* __restrict__ Kg,
        const u16* __restrict__ VTg, const float* __restrict__ dmb, u16* __restrict__ Og) {
    __shared__ alignas(16) u16 Ks[2][128 * 64];  // [buf][key][dh] rows 128B, chunk-swz
    __shared__ alignas(16) u16 Vs[2][64 * 128];  // [buf][dh][pos] rows 256B, pre-swz in VTg
    const int bh = blockIdx.x;
    const int qb = (int)gridDim.y - 1 - (int)blockIdx.y;  // heavy blocks first
    const int b = bh >> 4, h = bh & 15;
    const int tid = threadIdx.x, w = tid >> 6, lane = tid & 63;
    const int lr = lane & 15, lg = lane >> 4;
    const int q0 = qb * 64 + w * 16;
    const int qrow = q0 + lr;
    const u16* Qbase = Qg + ((size_t)bh * Tt + q0) * DHh;
    short8 qf0 = *(const short8*)(Qbase + lr * DHh + lg * 8);
    short8 qf1 = *(const short8*)(Qbase + lr * DHh + 32 + lg * 8);
    const f32x4 vzero = {0.f, 0.f, 0.f, 0.f};
    const short8 ones8 = {(short)0x3F80, (short)0x3F80, (short)0x3F80, (short)0x3F80,
                          (short)0x3F80, (short)0x3F80, (short)0x3F80, (short)0x3F80};
    f32x4 o[4];
#pragma unroll
    for (int n = 0; n < 4; ++n) o[n] = vzero;
    f32x4 acc_l = vzero;                          // l accumulates on MFMA pipe
    const int ktiles = (qb * 64 + 63) / 128 + 1;

#define STAGEKV(BUF, KT) do { \
    const int kb_ = (KT) * 128; \
    _Pragma("unroll") \
    for (int j_ = 0; j_ < 4; ++j_) { \
        int r0_ = w * 32 + j_ * 8; \
        int r_ = r0_ + (lane >> 3); \
        int cs_ = (lane & 7) ^ (r_ & 7); \
        gload16(Kg + ((size_t)bh * Tt + kb_ + r_) * DHh + cs_ * 8, (char*)&Ks[BUF][0] + r0_ * 128); \
    } \
    { \
        const u16* vsrc_ = VTg + (((size_t)bh * 16 + (KT)) * 8192) + w * 2048 + lane * 8; \
        _Pragma("unroll") \
        for (int j_ = 0; j_ < 4; ++j_) \
            gload16(vsrc_ + j_ * 512, (char*)&Vs[BUF][0] + w * 4096 + j_ * 1024); \
    } } while (0)

    STAGEKV(0, 0);
    __syncthreads();
    int buf = 0;
    for (int kt = 0; kt < ktiles; ++kt) {
        const int kbase = kt * 128;
        // prefetch next tile into the other buffer (latency hides under compute)
        if (kt + 1 < ktiles) { if (buf) STAGEKV(0, kt + 1); else STAGEKV(1, kt + 1); }
        const char* KsB = (const char*)&Ks[buf][0];
        const char* VsB = (const char*)&Vs[buf][0];
        // S^T = K Q^T + mask-bias (C-operand): lane q = lr, k = 16*nf + 4*lg + i
        f32x4 s[8];
        const float* bb = dmb + (size_t)b * Tt + kbase + 4 * lg;
#pragma unroll
        for (int nf = 0; nf < 8; ++nf) {
            int r = nf * 16 + lr;
            short8 k0v = *(const short8*)(KsB + r * 128 + (((0 + lg) ^ (r & 7)) << 4));
            short8 k1v = *(const short8*)(KsB + r * 128 + (((4 + lg) ^ (r & 7)) << 4));
            f32x4 cin = *(const f32x4*)(bb + nf * 16);
            f32x4 t0 = __builtin_amdgcn_mfma_f32_16x16x32_bf16(k0v, qf0, cin, 0, 0, 0);
            s[nf] = __builtin_amdgcn_mfma_f32_16x16x32_bf16(k1v, qf1, t0, 0, 0, 0);
        }
        // causal cut, diagonal tiles only (wave-uniform branch)
        if (kbase + 127 > q0) {
#pragma unroll
            for (int nf = 0; nf < 8; ++nf) {
                int tk = kbase + 16 * nf + 4 * lg;
#pragma unroll
                for (int i = 0; i < 4; ++i)
                    if (tk + i > qrow) s[nf][i] -= 15000.f;
            }
        }
        // PV: pf lane-local (pi-permuted keys), V read matches pi via VTg layout
#pragma unroll
        for (int ks = 0; ks < 4; ++ks) {
            union { uint4 u; short8 sv; } pf;
            pf.u.x = pk2bf(exp2f(s[2 * ks][0]), exp2f(s[2 * ks][1]));
            pf.u.y = pk2bf(exp2f(s[2 * ks][2]), exp2f(s[2 * ks][3]));
            pf.u.z = pk2bf(exp2f(s[2 * ks + 1][0]), exp2f(s[2 * ks + 1][1]));
            pf.u.w = pk2bf(exp2f(s[2 * ks + 1][2]), exp2f(s[2 * ks + 1][3]));
            acc_l = __builtin_amdgcn_mfma_f32_16x16x32_bf16(ones8, pf.sv, acc_l, 0, 0, 0);
#pragma unroll
            for (int n = 0; n < 4; ++n) {
                int rv = n * 16 + lr;
                short8 vf = *(const short8*)(VsB + rv * 256 + ((((ks * 4 + lg)) ^ (rv & 7)) << 4));
                o[n] = __builtin_amdgcn_mfma_f32_16x16x32_bf16(vf, pf.sv, o[n], 0, 0, 0);
            }
        }
        __syncthreads();   // drains prefetch vmcnt (after compute) + lgkm
        buf ^= 1;
    }
#undef STAGEKV
    // epilogue: normalize by l = acc_l[0] (same value across D rows), write O
    float l = acc_l[0];
    float inv = l > 0.f ? 1.0f / l : 0.f;
#pragma unroll
    for (int n = 0; n < 4; ++n) {
        uint2 pw;
        pw.x = pk2bf(o[n][0] * inv, o[n][1] * inv);
        pw.y = pk2bf(o[n][2] * inv, o[n][3] * inv);
        *(uint2*)(Og + ((size_t)(b * Tt + qrow)) * Dd + h * DHh + n * 16 + 4 * lg) = pw;
    }
}

// ---------------------------------------------------------------------------
// Output GEMM: O[4096,1024] @ Wp -> f32 out, + bp, * data_mask (m97 core)
// ---------------------------------------------------------------------------
__global__ __launch_bounds__(256) void out_gemm_k(const u16* __restrict__ Og, const u16* __restrict__ wpt,
        const float* __restrict__ bp, const int* __restrict__ dmask, float* __restrict__ out) {
    __shared__ alignas(16) u16 As[128 * 32];
    __shared__ alignas(16) u16 Bs[128 * 32];
    f32x4 acc[4][4];
    const f32x4 vzero = {0.f, 0.f, 0.f, 0.f};
#pragma unroll
    for (int m = 0; m < 4; ++m)
#pragma unroll
        for (int n = 0; n < 4; ++n) acc[m][n] = vzero;
    const int m0 = blockIdx.y * 128, n0 = blockIdx.x * 128;
    gemm_bt_core(Og, wpt, 1024, m0, n0, As, Bs, acc);
    const int tid = threadIdx.x, w = tid >> 6, lane = tid & 63, lr = lane & 15, lg = lane >> 4;
    const int wr = w >> 1, wc = w & 1;
#pragma unroll
    for (int n = 0; n < 4; ++n) {
        int gn = n0 + wc * 64 + n * 16 + lr;
        float bj = bp[gn];
#pragma unroll
        for (int m = 0; m < 4; ++m) {
            int gmb = m0 + wr * 64 + m * 16 + 4 * lg;
#pragma unroll
            for (int i = 0; i < 4; ++i) {
                int gm = gmb + i;
                float dmv = (float)dmask[gm];
                out[(size_t)gm * Dd + gn] = (acc[m][n][i] + bj) * dmv;
            }
        }
    }
}

// ---------------------------------------------------------------------------
// Workspace layout (bytes):
//   [0,8M)    xb  bf16 [4096][1024]   (reused as Og after qkv_gemm)
//   [8M,16M)  wt  bf16 [4][1024][1024] (WqT,WkT,WvT,WpT)
//   [16M,24M) Qg  bf16 [32][2048][64]  (scaled incl log2e)
//   [24M,32M) Kg  bf16 [32][2048][64]
//   [32M,40M) VTg bf16 [32][16][64][128] (V pre-permuted tiled, 16KB/tile)
//   [40M,+16K) dmb f32 [2][2048] additive mask bias
// ---------------------------------------------------------------------------
extern "C" void kernel_launch(void* const* d_in, const int* in_sizes, int n_in,
                              void* d_out, int out_size, void* d_ws, size_t ws_size,
                              hipStream_t stream) {
    const float* x   = (const float*)d_in[0];
    const int*  dmask = (const int*)d_in[1];
    const float* Wq = (const float*)d_in[2];
    const float* bq = (const float*)d_in[3];
    const float* Wk = (const float*)d_in[4];
    const float* bk = (const float*)d_in[5];
    const float* Wv = (const float*)d_in[6];
    const float* bv = (const float*)d_in[7];
    const float* Wp = (const float*)d_in[8];
    const float* bp = (const float*)d_in[9];
    float* out = (float*)d_out;
    char* ws = (char*)d_ws;
    u16* xb  = (u16*)(ws);
    u16* wt  = (u16*)(ws + ((size_t)8 << 20));
    u16* Qg  = (u16*)(ws + ((size_t)16 << 20));
    u16* Kg  = (u16*)(ws + ((size_t)24 << 20));
    u16* VTg = (u16*)(ws + ((size_t)32 << 20));
    float* dmb = (float*)(ws + ((size_t)40 << 20));
    u16* Og  = xb;   // reuse: xb consumed by qkv_gemm before attn writes Og

    convert_x_k<<<dim3(4096), dim3(256), 0, stream>>>((const float4*)x, (ushort4*)xb,
                                                      (Bb * Tt * Dd) / 4, dmask, dmb);
    transpose_w_k<<<dim3(32, 32, 4), dim3(32, 8), 0, stream>>>(Wq, Wk, Wv, Wp, wt);
    qkv_gemm_k<<<dim3(24, 32), dim3(256), 0, stream>>>(xb, wt, bq, bk, bv, Qg, Kg, VTg);
    attn_k<<<dim3(32, 32), dim3(256), 0, stream>>>(Qg, Kg, VTg, dmb, Og);
    out_gemm_k<<<dim3(8, 32), dim3(256), 0, stream>>>(Og, wt + (size_t)3 * Dd * Dd, bp, dmask, out);
}